// Round 2
// baseline (576.877 us; speedup 1.0000x reference)
//
#include <hip/hip_runtime.h>
#include <hip/hip_bf16.h>
#include <stdint.h>

#define S_LEN   2048
#define DIN     2048
#define NHEADS  32
#define HDIM    64
#define NKV     8

typedef __bf16 bf16x8 __attribute__((ext_vector_type(8)));
typedef float  f32x4  __attribute__((ext_vector_type(4)));

#define AS1(p) ((__attribute__((address_space(1))) void*)(void*)(p))
#define AS3(p) ((__attribute__((address_space(3))) void*)(p))
#define MFMA_BF16 __builtin_amdgcn_mfma_f32_16x16x32_bf16

static __device__ __forceinline__ unsigned short f2bf(float f) {
  unsigned int x = __float_as_uint(f);
  return (unsigned short)((x + 0x7fffu + ((x >> 16) & 1u)) >> 16);
}

// ---------------- cast x (fp32 -> bf16), vectorized ----------------
__global__ __launch_bounds__(256) void cast_x_kernel(const float* __restrict__ x,
                                                     unsigned short* __restrict__ xb, int n4) {
  int i = blockIdx.x * 256 + threadIdx.x;
  if (i >= n4) return;
  float4 f = ((const float4*)x)[i];
  ushort4 o = make_ushort4(f2bf(f.x), f2bf(f.y), f2bf(f.z), f2bf(f.w));
  ((ushort4*)xb)[i] = o;
}

// ---------------- transpose + cast: src fp32 [K][N] -> dst bf16 [N][K] ----------------
// grid (N/32, K/32), block (32, 8). dst leading dim = K.
__global__ __launch_bounds__(256) void transpose_cast(const float* __restrict__ src,
                                                      unsigned short* __restrict__ dst,
                                                      int K, int N) {
  __shared__ float t[32][33];
  int n0 = blockIdx.x * 32, k0 = blockIdx.y * 32;
  int x = threadIdx.x, y = threadIdx.y;
  #pragma unroll
  for (int j = 0; j < 32; j += 8)
    t[y + j][x] = src[(size_t)(k0 + y + j) * N + n0 + x];
  __syncthreads();
  #pragma unroll
  for (int j = 0; j < 32; j += 8)
    dst[(size_t)(n0 + y + j) * K + k0 + x] = f2bf(t[x][y + j]);
}

// ---------------- bf16 NT GEMM: C[M][N] fp32 = A[M][K] * Bt[N][K]^T ----------------
// m97 structure: 128x128 tile, BK=32, 256 thr (4 waves, each 64x64 = 4x4 of 16x16x32).
__global__ __launch_bounds__(256) void gemm_nt(const unsigned short* __restrict__ A,
                                               const unsigned short* __restrict__ Bt,
                                               float* __restrict__ C,
                                               int M, int N, int K) {
  __shared__ alignas(16) unsigned short As[128 * 32];
  __shared__ alignas(16) unsigned short Bs[128 * 32];
  const int tid = threadIdx.x;
  const int wave = tid >> 6, lane = tid & 63;
  const int g = lane >> 4, c = lane & 15;
  const int m0 = blockIdx.y * 128, n0 = blockIdx.x * 128;
  const int wm = (wave & 1) * 64, wn = (wave >> 1) * 64;

  f32x4 acc[4][4] = {};

  const int ch0 = wave * 2, ch1 = ch0 + 1;
  const int e0 = ch0 * 512 + lane * 8, e1 = e0 + 512;
  const int r0 = e0 >> 5, c0 = e0 & 31;
  const int r1 = e1 >> 5, c1 = e1 & 31;
  const unsigned short* a0 = A + (size_t)(m0 + r0) * K + c0;
  const unsigned short* a1 = A + (size_t)(m0 + r1) * K + c1;
  const unsigned short* b0 = Bt + (size_t)(n0 + r0) * K + c0;
  const unsigned short* b1 = Bt + (size_t)(n0 + r1) * K + c1;

  for (int k0 = 0; k0 < K; k0 += 32) {
    __syncthreads();
    __builtin_amdgcn_global_load_lds(AS1(a0 + k0), AS3(As + ch0 * 512), 16, 0, 0);
    __builtin_amdgcn_global_load_lds(AS1(a1 + k0), AS3(As + ch1 * 512), 16, 0, 0);
    __builtin_amdgcn_global_load_lds(AS1(b0 + k0), AS3(Bs + ch0 * 512), 16, 0, 0);
    __builtin_amdgcn_global_load_lds(AS1(b1 + k0), AS3(Bs + ch1 * 512), 16, 0, 0);
    __builtin_amdgcn_s_waitcnt(0);
    __syncthreads();

    bf16x8 af[4], bfr[4];
    #pragma unroll
    for (int i = 0; i < 4; i++)
      af[i] = *(const bf16x8*)(As + (wm + i * 16 + c) * 32 + g * 8);
    #pragma unroll
    for (int j = 0; j < 4; j++)
      bfr[j] = *(const bf16x8*)(Bs + (wn + j * 16 + c) * 32 + g * 8);
    #pragma unroll
    for (int i = 0; i < 4; i++)
      #pragma unroll
      for (int j = 0; j < 4; j++)
        acc[i][j] = MFMA_BF16(af[i], bfr[j], acc[i][j], 0, 0, 0);
  }

  #pragma unroll
  for (int i = 0; i < 4; i++)
    #pragma unroll
    for (int j = 0; j < 4; j++)
      #pragma unroll
      for (int r = 0; r < 4; r++)
        C[(size_t)(m0 + wm + i * 16 + g * 4 + r) * N + n0 + wn + j * 16 + c] = acc[i][j][r];
}

// ---------------- RMSNorm + RoPE for Q and K heads ----------------
// one wave per (token-row, head-slot); head-slot 0..31 = Q heads, 32..39 = K heads.
__global__ __launch_bounds__(256) void norm_rope(const float* __restrict__ QKV,
                                                 const float* __restrict__ cosb,
                                                 const float* __restrict__ sinb,
                                                 const float* __restrict__ q_scale,
                                                 const float* __restrict__ k_scale,
                                                 unsigned short* __restrict__ Qn,
                                                 unsigned short* __restrict__ Kn) {
  const int tid = threadIdx.x, w = tid >> 6, d = tid & 63;
  int task = blockIdx.x * 4 + w;
  const int hid = task % 40;
  const int row = task / 40;            // b*2048 + s
  const int b = row >> 11, s = row & 2047;
  float val, sc;
  if (hid < 32) {
    val = QKV[(size_t)row * 3072 + hid * 64 + d];
    sc = q_scale[d];
  } else {
    val = QKV[(size_t)row * 3072 + 2048 + (hid - 32) * 64 + d];
    sc = k_scale[d];
  }
  float v2 = val * val;
  #pragma unroll
  for (int off = 32; off; off >>= 1) v2 += __shfl_xor(v2, off);
  float t = val * (1.0f / sqrtf(v2 * (1.0f / 64.0f) + 1e-6f)) * sc;
  float partner = __shfl_xor(t, 32);
  float rot = (d < 32) ? -partner : partner;
  float o = t * cosb[s * 64 + d] + rot * sinb[s * 64 + d];
  unsigned short ob = f2bf(o);
  if (hid < 32) Qn[((size_t)(b * 32 + hid) * 2048 + s) * 64 + d] = ob;
  else          Kn[((size_t)(b * 8 + (hid - 32)) * 2048 + s) * 64 + d] = ob;
}

// ---------------- V transpose+cast: QKV fp32 V-cols -> Vt bf16 [b][kv][D][S] ----------------
__global__ __launch_bounds__(256) void v_transpose(const float* __restrict__ QKV,
                                                   unsigned short* __restrict__ Vt) {
  __shared__ float t[64][65];
  int bid = blockIdx.x;
  const int st = bid & 31, kv = (bid >> 5) & 7, b = bid >> 8;
  const int tid = threadIdx.x, lane = tid & 63, quad = tid >> 6;
  #pragma unroll
  for (int p = 0; p < 16; p++) {
    int sl = p * 4 + quad;
    t[sl][lane] = QKV[(size_t)(b * 2048 + st * 64 + sl) * 3072 + 2560 + kv * 64 + lane];
  }
  __syncthreads();
  size_t base = (size_t)(b * 8 + kv) * 64 * 2048;
  #pragma unroll
  for (int p = 0; p < 16; p++) {
    int dd = p * 4 + quad;
    Vt[base + (size_t)dd * 2048 + st * 64 + lane] = f2bf(t[lane][dd]);
  }
}

// ---------------- causal flash attention, bf16 MFMA ----------------
// block = (b, h, q-tile of 128); 4 waves x 32 q rows; kv tiles of 64.
__global__ __launch_bounds__(256) void attn_kernel(const unsigned short* __restrict__ Qn,
                                                   const unsigned short* __restrict__ Kn,
                                                   const unsigned short* __restrict__ Vt,
                                                   unsigned short* __restrict__ Outv) {
  __shared__ alignas(16) unsigned short Ks[64 * 64];
  __shared__ alignas(16) unsigned short Vs[64 * 64];   // [d][kv]
  __shared__ alignas(16) unsigned short Ps[4 * 32 * 64];
  const int tid = threadIdx.x, w = tid >> 6, lane = tid & 63;
  const int g = lane >> 4, c = lane & 15;
  const int bid = blockIdx.x;
  const int qt = bid & 15, h = (bid >> 4) & 31, b = bid >> 9;
  const int kvh = h >> 2;
  const unsigned short* Qp = Qn + (size_t)(b * NHEADS + h) * S_LEN * HDIM;
  const unsigned short* Kp = Kn + (size_t)(b * NKV + kvh) * S_LEN * HDIM;
  const unsigned short* Vp = Vt + (size_t)(b * NKV + kvh) * HDIM * S_LEN;
  const int qw = qt * 128 + w * 32;

  bf16x8 aq[2][2];
  #pragma unroll
  for (int i = 0; i < 2; i++)
    #pragma unroll
    for (int t = 0; t < 2; t++)
      aq[i][t] = *(const bf16x8*)(Qp + (size_t)(qw + i * 16 + c) * HDIM + t * 32 + g * 8);

  f32x4 O[2][4] = {};
  f32x4 mrow[2], lrow[2];
  #pragma unroll
  for (int i = 0; i < 2; i++)
    #pragma unroll
    for (int r = 0; r < 4; r++) { mrow[i][r] = -1e30f; lrow[i][r] = 0.f; }
  const float SC = 0.18033688011112042f;   // log2(e) / sqrt(64)

  const int kv_end = qt * 128 + 128;
  for (int kv0 = 0; kv0 < kv_end; kv0 += 64) {
    __syncthreads();
    #pragma unroll
    for (int cc = 0; cc < 2; cc++) {
      int ch = w * 2 + cc;
      int ee = ch * 512 + lane * 8;
      int row = ee >> 6, col = ee & 63;
      __builtin_amdgcn_global_load_lds(AS1(Kp + (size_t)(kv0 + row) * HDIM + col),
                                       AS3(Ks + ch * 512), 16, 0, 0);
      __builtin_amdgcn_global_load_lds(AS1(Vp + (size_t)row * S_LEN + kv0 + col),
                                       AS3(Vs + ch * 512), 16, 0, 0);
    }
    __builtin_amdgcn_s_waitcnt(0);
    __syncthreads();

    if (kv0 <= qw + 31) {                 // wave-uniform causal skip
      f32x4 Sx[2][4] = {};
      #pragma unroll
      for (int t = 0; t < 2; t++)
        #pragma unroll
        for (int j = 0; j < 4; j++) {
          bf16x8 bk = *(const bf16x8*)(Ks + (j * 16 + c) * 64 + t * 32 + g * 8);
          Sx[0][j] = MFMA_BF16(aq[0][t], bk, Sx[0][j], 0, 0, 0);
          Sx[1][j] = MFMA_BF16(aq[1][t], bk, Sx[1][j], 0, 0, 0);
        }

      #pragma unroll
      for (int i = 0; i < 2; i++) {
        f32x4 tmax;
        #pragma unroll
        for (int r = 0; r < 4; r++) {
          int q = qw + i * 16 + g * 4 + r;
          float best = -1e30f;
          #pragma unroll
          for (int j = 0; j < 4; j++) {
            int kv = kv0 + j * 16 + c;
            float u = (kv <= q) ? Sx[i][j][r] * SC : -1e30f;
            Sx[i][j][r] = u;
            best = fmaxf(best, u);
          }
          tmax[r] = best;
        }
        #pragma unroll
        for (int off = 1; off < 16; off <<= 1)
          #pragma unroll
          for (int r = 0; r < 4; r++) tmax[r] = fmaxf(tmax[r], __shfl_xor(tmax[r], off));

        f32x4 nm, alpha, rs;
        #pragma unroll
        for (int r = 0; r < 4; r++) {
          nm[r] = fmaxf(mrow[i][r], tmax[r]);
          alpha[r] = exp2f(mrow[i][r] - nm[r]);
          mrow[i][r] = nm[r];
          rs[r] = 0.f;
        }
        #pragma unroll
        for (int j = 0; j < 4; j++)
          #pragma unroll
          for (int r = 0; r < 4; r++) {
            float p = exp2f(Sx[i][j][r] - nm[r]);
            Sx[i][j][r] = p;
            rs[r] += p;
          }
        #pragma unroll
        for (int off = 1; off < 16; off <<= 1)
          #pragma unroll
          for (int r = 0; r < 4; r++) rs[r] += __shfl_xor(rs[r], off);
        #pragma unroll
        for (int r = 0; r < 4; r++) lrow[i][r] = lrow[i][r] * alpha[r] + rs[r];
        #pragma unroll
        for (int jd = 0; jd < 4; jd++)
          #pragma unroll
          for (int r = 0; r < 4; r++) O[i][jd][r] *= alpha[r];
        #pragma unroll
        for (int j = 0; j < 4; j++)
          #pragma unroll
          for (int r = 0; r < 4; r++)
            Ps[(w * 32 + i * 16 + g * 4 + r) * 64 + j * 16 + c] = f2bf(Sx[i][j][r]);
      }
      __builtin_amdgcn_s_waitcnt(0);      // drain Ps writes (wave-private region)

      #pragma unroll
      for (int t = 0; t < 2; t++) {
        bf16x8 ap0 = *(const bf16x8*)(Ps + (w * 32 + 0 + c) * 64 + t * 32 + g * 8);
        bf16x8 ap1 = *(const bf16x8*)(Ps + (w * 32 + 16 + c) * 64 + t * 32 + g * 8);
        #pragma unroll
        for (int jd = 0; jd < 4; jd++) {
          bf16x8 bv = *(const bf16x8*)(Vs + (jd * 16 + c) * 64 + t * 32 + g * 8);
          O[0][jd] = MFMA_BF16(ap0, bv, O[0][jd], 0, 0, 0);
          O[1][jd] = MFMA_BF16(ap1, bv, O[1][jd], 0, 0, 0);
        }
      }
    }
  }

  #pragma unroll
  for (int i = 0; i < 2; i++) {
    f32x4 inv;
    #pragma unroll
    for (int r = 0; r < 4; r++) inv[r] = 1.0f / lrow[i][r];
    #pragma unroll
    for (int jd = 0; jd < 4; jd++)
      #pragma unroll
      for (int r = 0; r < 4; r++) {
        int q = qw + i * 16 + g * 4 + r;
        Outv[(size_t)(b * S_LEN + q) * (NHEADS * HDIM) + h * HDIM + jd * 16 + c] =
            f2bf(O[i][jd][r] * inv[r]);
      }
  }
}

extern "C" void kernel_launch(void* const* d_in, const int* in_sizes, int n_in,
                              void* d_out, int out_size, void* d_ws, size_t ws_size,
                              hipStream_t stream) {
  const float* x       = (const float*)d_in[0];
  // d_in[1] = mask (causal, implemented analytically)
  const float* cosb    = (const float*)d_in[2];
  const float* sinb    = (const float*)d_in[3];
  const float* Wq      = (const float*)d_in[4];
  const float* Wk      = (const float*)d_in[5];
  const float* Wv      = (const float*)d_in[6];
  const float* Wo      = (const float*)d_in[7];
  const float* q_scale = (const float*)d_in[8];
  const float* k_scale = (const float*)d_in[9];

  char* ws = (char*)d_ws;
  unsigned short* xb   = (unsigned short*)(ws);                       // 16 MiB: x bf16 [4096][2048]
  unsigned short* wcat = (unsigned short*)(ws + (16ull << 20));       // 12 MiB: Wt [3072][2048]
  unsigned short* wo_t = (unsigned short*)(ws + (28ull << 20));       //  8 MiB: Wo_t [2048][2048]
  float*          qkv  = (float*)        (ws + (36ull << 20));        // 48 MiB: QKV fp32 [4096][3072]
  unsigned short* qn   = (unsigned short*)(ws + (84ull << 20));       // 16 MiB: Q bf16 [b][h][s][d]
  unsigned short* kn   = (unsigned short*)(ws + (100ull << 20));      //  4 MiB: K bf16 [b][kv][s][d]
  unsigned short* vt   = (unsigned short*)(ws + (104ull << 20));      //  4 MiB: V^T bf16 [b][kv][d][s]
  unsigned short* vec  = (unsigned short*)(ws + (36ull << 20));       // alias qkv (dead after v_transpose)

  cast_x_kernel<<<8192, 256, 0, stream>>>(x, xb, 2097152);
  dim3 tb(32, 8);
  transpose_cast<<<dim3(64, 64), tb, 0, stream>>>(Wq, wcat,               2048, 2048);
  transpose_cast<<<dim3(16, 64), tb, 0, stream>>>(Wk, wcat + 2048 * 2048, 2048, 512);
  transpose_cast<<<dim3(16, 64), tb, 0, stream>>>(Wv, wcat + 2560 * 2048, 2048, 512);
  transpose_cast<<<dim3(64, 64), tb, 0, stream>>>(Wo, wo_t,               2048, 2048);

  gemm_nt<<<dim3(24, 32), 256, 0, stream>>>(xb, wcat, qkv, 4096, 3072, 2048);
  norm_rope<<<40960, 256, 0, stream>>>(qkv, cosb, sinb, q_scale, k_scale, qn, kn);
  v_transpose<<<512, 256, 0, stream>>>(qkv, vt);
  attn_kernel<<<1024, 256, 0, stream>>>(qn, kn, vt, vec);
  gemm_nt<<<dim3(16, 32), 256, 0, stream>>>(vec, wo_t, (float*)d_out, 4096, 2048, 2048);
}

// Round 3
// 438.246 us; speedup vs baseline: 1.3163x; 1.3163x over previous
//
#include <hip/hip_runtime.h>
#include <hip/hip_bf16.h>
#include <stdint.h>

#define S_LEN   2048
#define DIN     2048
#define NHEADS  32
#define HDIM    64
#define NKV     8

typedef __bf16 bf16x8 __attribute__((ext_vector_type(8)));
typedef float  f32x4  __attribute__((ext_vector_type(4)));

#define AS1(p) ((__attribute__((address_space(1))) void*)(void*)(p))
#define AS3(p) ((__attribute__((address_space(3))) void*)(p))
#define MFMA_BF16 __builtin_amdgcn_mfma_f32_16x16x32_bf16

static __device__ __forceinline__ unsigned short f2bf(float f) {
  unsigned int x = __float_as_uint(f);
  return (unsigned short)((x + 0x7fffu + ((x >> 16) & 1u)) >> 16);
}

// ---------------- cast x (fp32 -> bf16), vectorized ----------------
__global__ __launch_bounds__(256) void cast_x_kernel(const float* __restrict__ x,
                                                     unsigned short* __restrict__ xb, int n4) {
  int i = blockIdx.x * 256 + threadIdx.x;
  if (i >= n4) return;
  float4 f = ((const float4*)x)[i];
  ushort4 o = make_ushort4(f2bf(f.x), f2bf(f.y), f2bf(f.z), f2bf(f.w));
  ((ushort4*)xb)[i] = o;
}

// ---------------- transpose + cast: src fp32 [K][N] -> dst bf16 [N][K] ----------------
__global__ __launch_bounds__(256) void transpose_cast(const float* __restrict__ src,
                                                      unsigned short* __restrict__ dst,
                                                      int K, int N) {
  __shared__ float t[32][33];
  int n0 = blockIdx.x * 32, k0 = blockIdx.y * 32;
  int x = threadIdx.x, y = threadIdx.y;
  #pragma unroll
  for (int j = 0; j < 32; j += 8)
    t[y + j][x] = src[(size_t)(k0 + y + j) * N + n0 + x];
  __syncthreads();
  #pragma unroll
  for (int j = 0; j < 32; j += 8)
    dst[(size_t)(n0 + y + j) * K + k0 + x] = f2bf(t[x][y + j]);
}

// ---------------- bf16 NT GEMM: C[M][N] fp32 = A[M][K] * Bt[N][K]^T ----------------
// m97 structure + XOR-swizzled LDS (swizzle realized via per-lane global address
// permutation in global_load_lds; consumer reads land 2-way/bank = free).
// Physical 16B-chunk layout: chunk(row, grp) = row*4 + (grp ^ ((row>>1)&3)).
__global__ __launch_bounds__(256) void gemm_nt(const unsigned short* __restrict__ A,
                                               const unsigned short* __restrict__ Bt,
                                               float* __restrict__ C,
                                               int M, int N, int K) {
  __shared__ alignas(16) unsigned short As[128 * 32];
  __shared__ alignas(16) unsigned short Bs[128 * 32];
  const int tid = threadIdx.x;
  const int wave = tid >> 6, lane = tid & 63;
  const int g = lane >> 4, c = lane & 15;
  const int m0 = blockIdx.y * 128, n0 = blockIdx.x * 128;
  const int wm = (wave & 1) * 64, wn = (wave >> 1) * 64;

  f32x4 acc[4][4] = {};

  const int ch0 = wave * 2;
  const int p0 = ch0 * 64 + lane, p1 = p0 + 64;
  const int r0 = p0 >> 2, gc0 = ((p0 & 3) ^ ((r0 >> 1) & 3)) * 8;
  const int r1 = p1 >> 2, gc1 = ((p1 & 3) ^ ((r1 >> 1) & 3)) * 8;
  const unsigned short* a0 = A + (size_t)(m0 + r0) * K + gc0;
  const unsigned short* a1 = A + (size_t)(m0 + r1) * K + gc1;
  const unsigned short* b0 = Bt + (size_t)(n0 + r0) * K + gc0;
  const unsigned short* b1 = Bt + (size_t)(n0 + r1) * K + gc1;
  const int fswz = (c >> 1) & 3;   // f(row) for consumer rows (wm,i*16 are mult of 16)

  for (int k0 = 0; k0 < K; k0 += 32) {
    __syncthreads();
    __builtin_amdgcn_global_load_lds(AS1(a0 + k0), AS3(As + ch0 * 512), 16, 0, 0);
    __builtin_amdgcn_global_load_lds(AS1(a1 + k0), AS3(As + ch0 * 512 + 512), 16, 0, 0);
    __builtin_amdgcn_global_load_lds(AS1(b0 + k0), AS3(Bs + ch0 * 512), 16, 0, 0);
    __builtin_amdgcn_global_load_lds(AS1(b1 + k0), AS3(Bs + ch0 * 512 + 512), 16, 0, 0);
    __builtin_amdgcn_s_waitcnt(0);
    __syncthreads();

    bf16x8 af[4], bfr[4];
    #pragma unroll
    for (int i = 0; i < 4; i++)
      af[i] = *(const bf16x8*)(As + (wm + i * 16 + c) * 32 + (g ^ fswz) * 8);
    #pragma unroll
    for (int j = 0; j < 4; j++)
      bfr[j] = *(const bf16x8*)(Bs + (wn + j * 16 + c) * 32 + (g ^ fswz) * 8);
    #pragma unroll
    for (int i = 0; i < 4; i++)
      #pragma unroll
      for (int j = 0; j < 4; j++)
        acc[i][j] = MFMA_BF16(af[i], bfr[j], acc[i][j], 0, 0, 0);
  }

  #pragma unroll
  for (int i = 0; i < 4; i++)
    #pragma unroll
    for (int j = 0; j < 4; j++)
      #pragma unroll
      for (int r = 0; r < 4; r++)
        C[(size_t)(m0 + wm + i * 16 + g * 4 + r) * N + n0 + wn + j * 16 + c] = acc[i][j][r];
}

// ---------------- RMSNorm + RoPE for Q and K heads ----------------
// SC = log2(e)/sqrt(64) folded into Q here (attention uses exp2 with fixed max 0).
__global__ __launch_bounds__(256) void norm_rope(const float* __restrict__ QKV,
                                                 const float* __restrict__ cosb,
                                                 const float* __restrict__ sinb,
                                                 const float* __restrict__ q_scale,
                                                 const float* __restrict__ k_scale,
                                                 unsigned short* __restrict__ Qn,
                                                 unsigned short* __restrict__ Kn) {
  const int tid = threadIdx.x, w = tid >> 6, d = tid & 63;
  int task = blockIdx.x * 4 + w;
  const int hid = task % 40;
  const int row = task / 40;            // b*2048 + s
  const int b = row >> 11, s = row & 2047;
  float val, sc;
  if (hid < 32) {
    val = QKV[(size_t)row * 3072 + hid * 64 + d];
    sc = q_scale[d];
  } else {
    val = QKV[(size_t)row * 3072 + 2048 + (hid - 32) * 64 + d];
    sc = k_scale[d];
  }
  float v2 = val * val;
  #pragma unroll
  for (int off = 32; off; off >>= 1) v2 += __shfl_xor(v2, off);
  float t = val * (1.0f / sqrtf(v2 * (1.0f / 64.0f) + 1e-6f)) * sc;
  float partner = __shfl_xor(t, 32);
  float rot = (d < 32) ? -partner : partner;
  float o = t * cosb[s * 64 + d] + rot * sinb[s * 64 + d];
  if (hid < 32) o *= 0.18033688011112042f;   // fold softmax scale into Q
  unsigned short ob = f2bf(o);
  if (hid < 32) Qn[((size_t)(b * 32 + hid) * 2048 + s) * 64 + d] = ob;
  else          Kn[((size_t)(b * 8 + (hid - 32)) * 2048 + s) * 64 + d] = ob;
}

// ---------------- V transpose+cast: QKV fp32 V-cols -> Vt bf16 [b][kv][D][S] ----------------
__global__ __launch_bounds__(256) void v_transpose(const float* __restrict__ QKV,
                                                   unsigned short* __restrict__ Vt) {
  __shared__ float t[64][65];
  int bid = blockIdx.x;
  const int st = bid & 31, kv = (bid >> 5) & 7, b = bid >> 8;
  const int tid = threadIdx.x, lane = tid & 63, quad = tid >> 6;
  #pragma unroll
  for (int p = 0; p < 16; p++) {
    int sl = p * 4 + quad;
    t[sl][lane] = QKV[(size_t)(b * 2048 + st * 64 + sl) * 3072 + 2560 + kv * 64 + lane];
  }
  __syncthreads();
  size_t base = (size_t)(b * 8 + kv) * 64 * 2048;
  #pragma unroll
  for (int p = 0; p < 16; p++) {
    int dd = p * 4 + quad;
    Vt[base + (size_t)dd * 2048 + st * 64 + lane] = f2bf(t[lane][dd]);
  }
}

// ---------------- causal flash attention v2: barrier-free kv loop ----------------
// Block = 32 q rows of one head. 4 waves stride kv tiles (64 wide) independently:
// fixed-max softmax (p = exp2(s), no running max) makes kv accumulation order-free.
// S^T orientation (K·Q^T): q in lane dim -> P rows kv-contiguous -> b64 LDS writes.
// K/V read global->VGPR directly (L2-resident). P round-trips via XOR-swizzled LDS.
// Waves combine (O, l) through LDS once at the end.
__global__ __launch_bounds__(256) void attn_kernel(const unsigned short* __restrict__ Qn,
                                                   const unsigned short* __restrict__ Kn,
                                                   const unsigned short* __restrict__ Vt,
                                                   unsigned short* __restrict__ Outv) {
  // per-wave region (8704 B) holds Ps (4 KB, loop) then Obuf (8.5 KB, epilogue)
  __shared__ alignas(16) char smem[4 * 8704 + 512];
  float* Ls_ = (float*)(smem + 4 * 8704);          // [4][32]

  const int tid = threadIdx.x, w = tid >> 6, lane = tid & 63;
  const int g = lane >> 4, c = lane & 15;
  const int bid = blockIdx.x;
  const int qt = 63 - (bid >> 6);                  // longest blocks first
  const int h = (bid >> 1) & 31, b = bid & 1;
  const int kvh = h >> 2;
  const int Q0 = qt * 32;
  const unsigned short* Qp = Qn + ((size_t)(b * NHEADS + h) * S_LEN + Q0) * HDIM;
  const unsigned short* Kp = Kn + (size_t)(b * NKV + kvh) * S_LEN * HDIM;
  const unsigned short* Vp = Vt + (size_t)(b * NKV + kvh) * HDIM * S_LEN;  // [d][s]
  const int ntiles = (qt >> 1) + 1;

  // Q as B-operand: B[k=d][n=q], n = c, k = g*8+j (+t*32)
  bf16x8 bq[2][2];
  #pragma unroll
  for (int iq = 0; iq < 2; iq++)
    #pragma unroll
    for (int t = 0; t < 2; t++)
      bq[iq][t] = *(const bf16x8*)(Qp + (size_t)(iq * 16 + c) * HDIM + t * 32 + g * 8);

  f32x4 OT[4][2] = {};          // O^T tiles: [dt][iq], row=d, col=q
  float lsum[2] = {0.f, 0.f};
  char* PwB = smem + w * 8704;  // this wave's P buffer (32 rows x 128 B, swizzled)

  for (int ti = w; ti < ntiles; ti += 4) {
    const int kv0 = ti * 64;
    // K as A-operand: A[m=kv][k=d]  (global b128, rows of Kn)
    bf16x8 ak[4][2];
    #pragma unroll
    for (int jt = 0; jt < 4; jt++)
      #pragma unroll
      for (int t = 0; t < 2; t++)
        ak[jt][t] = *(const bf16x8*)(Kp + (size_t)(kv0 + jt * 16 + c) * HDIM + t * 32 + g * 8);

    // S^T = K · Q^T : rows kv, cols q
    f32x4 Sx[4][2] = {};
    #pragma unroll
    for (int t = 0; t < 2; t++)
      #pragma unroll
      for (int jt = 0; jt < 4; jt++)
        #pragma unroll
        for (int iq = 0; iq < 2; iq++)
          Sx[jt][iq] = MFMA_BF16(ak[jt][t], bq[iq][t], Sx[jt][iq], 0, 0, 0);

    if (ti == ntiles - 1) {     // only the final tile crosses the diagonal
      #pragma unroll
      for (int jt = 0; jt < 4; jt++)
        #pragma unroll
        for (int iq = 0; iq < 2; iq++)
          #pragma unroll
          for (int r = 0; r < 4; r++) {
            int kv = kv0 + jt * 16 + g * 4 + r;
            int q  = Q0 + iq * 16 + c;
            if (kv > q) Sx[jt][iq][r] = -1e30f;
          }
    }

    // V as A-operand: A[m=d][k=kv]  (global b128, rows of Vt)
    bf16x8 av[4][2];
    #pragma unroll
    for (int dt = 0; dt < 4; dt++)
      #pragma unroll
      for (int t = 0; t < 2; t++)
        av[dt][t] = *(const bf16x8*)(Vp + (size_t)(dt * 16 + c) * S_LEN + kv0 + t * 32 + g * 8);

    // fixed-max softmax: p = exp2(s); accumulate l per-lane; pack P -> LDS (swizzled)
    #pragma unroll
    for (int jt = 0; jt < 4; jt++)
      #pragma unroll
      for (int iq = 0; iq < 2; iq++) {
        f32x4 p;
        #pragma unroll
        for (int r = 0; r < 4; r++) {
          float e = exp2f(Sx[jt][iq][r]);
          p[r] = e;
          lsum[iq] += e;
        }
        uint32_t lo = (uint32_t)f2bf(p[0]) | ((uint32_t)f2bf(p[1]) << 16);
        uint32_t hi = (uint32_t)f2bf(p[2]) | ((uint32_t)f2bf(p[3]) << 16);
        int row = iq * 16 + c;                 // local q
        int bytecol = jt * 32 + g * 8;         // kv-contiguous bytes
        uint32_t off = row * 128 + (((bytecol >> 4) ^ (row & 7)) << 4) + (bytecol & 15);
        *(uint2*)(PwB + off) = make_uint2(lo, hi);
      }

    // P as B-operand: B[k=kv][n=q]; read back swizzled b128 (wave-private, no barrier)
    bf16x8 bp[2][2];
    #pragma unroll
    for (int iq = 0; iq < 2; iq++)
      #pragma unroll
      for (int t = 0; t < 2; t++) {
        int row = iq * 16 + c;
        int bytecol = t * 64 + g * 16;
        uint32_t off = row * 128 + (((bytecol >> 4) ^ (row & 7)) << 4);
        bp[iq][t] = *(const bf16x8*)(PwB + off);
      }
    #pragma unroll
    for (int t = 0; t < 2; t++)
      #pragma unroll
      for (int dt = 0; dt < 4; dt++)
        #pragma unroll
        for (int iq = 0; iq < 2; iq++)
          OT[dt][iq] = MFMA_BF16(av[dt][t], bp[iq][t], OT[dt][iq], 0, 0, 0);
  }

  // reduce l across the 4 lane-groups (kv was split across g)
  #pragma unroll
  for (int iq = 0; iq < 2; iq++) {
    lsum[iq] += __shfl_xor(lsum[iq], 16);
    lsum[iq] += __shfl_xor(lsum[iq], 32);
  }
  if (g == 0) { Ls_[w * 32 + c] = lsum[0]; Ls_[w * 32 + 16 + c] = lsum[1]; }

  // per-wave partial O^T -> LDS (fp32, stride 68 floats to dodge banks)
  float* Ow = (float*)(smem + w * 8704);
  #pragma unroll
  for (int dt = 0; dt < 4; dt++)
    #pragma unroll
    for (int iq = 0; iq < 2; iq++) {
      int q = iq * 16 + c;
      *(float2*)&Ow[q * 68 + dt * 16 + g * 4]     = make_float2(OT[dt][iq][0], OT[dt][iq][1]);
      *(float2*)&Ow[q * 68 + dt * 16 + g * 4 + 2] = make_float2(OT[dt][iq][2], OT[dt][iq][3]);
    }
  __syncthreads();

  // combine 4 waves, divide by l, write bf16
  const int q = tid >> 3, d0 = (tid & 7) * 8;
  float l = Ls_[q] + Ls_[32 + q] + Ls_[64 + q] + Ls_[96 + q];
  float inv = 1.0f / l;
  float acc[8] = {};
  #pragma unroll
  for (int ww = 0; ww < 4; ww++) {
    const float* Oww = (const float*)(smem + ww * 8704);
    f32x4 u0 = *(const f32x4*)&Oww[q * 68 + d0];
    f32x4 u1 = *(const f32x4*)&Oww[q * 68 + d0 + 4];
    #pragma unroll
    for (int k = 0; k < 4; k++) { acc[k] += u0[k]; acc[4 + k] += u1[k]; }
  }
  unsigned short ob[8];
  #pragma unroll
  for (int k = 0; k < 8; k++) ob[k] = f2bf(acc[k] * inv);
  uint4 pk = make_uint4((uint32_t)ob[0] | ((uint32_t)ob[1] << 16),
                        (uint32_t)ob[2] | ((uint32_t)ob[3] << 16),
                        (uint32_t)ob[4] | ((uint32_t)ob[5] << 16),
                        (uint32_t)ob[6] | ((uint32_t)ob[7] << 16));
  *(uint4*)(Outv + (size_t)(b * S_LEN + Q0 + q) * (NHEADS * HDIM) + h * HDIM + d0) = pk;
}

extern "C" void kernel_launch(void* const* d_in, const int* in_sizes, int n_in,
                              void* d_out, int out_size, void* d_ws, size_t ws_size,
                              hipStream_t stream) {
  const float* x       = (const float*)d_in[0];
  // d_in[1] = mask (causal, implemented analytically)
  const float* cosb    = (const float*)d_in[2];
  const float* sinb    = (const float*)d_in[3];
  const float* Wq      = (const float*)d_in[4];
  const float* Wk      = (const float*)d_in[5];
  const float* Wv      = (const float*)d_in[6];
  const float* Wo      = (const float*)d_in[7];
  const float* q_scale = (const float*)d_in[8];
  const float* k_scale = (const float*)d_in[9];

  char* ws = (char*)d_ws;
  unsigned short* xb   = (unsigned short*)(ws);                       // 16 MiB: x bf16 [4096][2048]
  unsigned short* wcat = (unsigned short*)(ws + (16ull << 20));       // 12 MiB: Wt [3072][2048]
  unsigned short* wo_t = (unsigned short*)(ws + (28ull << 20));       //  8 MiB: Wo_t [2048][2048]
  float*          qkv  = (float*)        (ws + (36ull << 20));        // 48 MiB: QKV fp32 [4096][3072]
  unsigned short* qn   = (unsigned short*)(ws + (84ull << 20));       // 16 MiB: Q bf16 [b][h][s][d]
  unsigned short* kn   = (unsigned short*)(ws + (100ull << 20));      //  4 MiB: K bf16 [b][kv][s][d]
  unsigned short* vt   = (unsigned short*)(ws + (104ull << 20));      //  4 MiB: V^T bf16 [b][kv][d][s]
  unsigned short* vec  = (unsigned short*)(ws + (36ull << 20));       // alias qkv (dead after v_transpose)

  cast_x_kernel<<<8192, 256, 0, stream>>>(x, xb, 2097152);
  dim3 tb(32, 8);
  transpose_cast<<<dim3(64, 64), tb, 0, stream>>>(Wq, wcat,               2048, 2048);
  transpose_cast<<<dim3(16, 64), tb, 0, stream>>>(Wk, wcat + 2048 * 2048, 2048, 512);
  transpose_cast<<<dim3(16, 64), tb, 0, stream>>>(Wv, wcat + 2560 * 2048, 2048, 512);
  transpose_cast<<<dim3(64, 64), tb, 0, stream>>>(Wo, wo_t,               2048, 2048);

  gemm_nt<<<dim3(24, 32), 256, 0, stream>>>(xb, wcat, qkv, 4096, 3072, 2048);
  norm_rope<<<40960, 256, 0, stream>>>(qkv, cosb, sinb, q_scale, k_scale, qn, kn);
  v_transpose<<<512, 256, 0, stream>>>(qkv, vt);
  attn_kernel<<<4096, 256, 0, stream>>>(qn, kn, vt, vec);
  gemm_nt<<<dim3(16, 32), 256, 0, stream>>>(vec, wo_t, (float*)d_out, 4096, 2048, 2048);
}

// Round 4
// 428.355 us; speedup vs baseline: 1.3467x; 1.0231x over previous
//
#include <hip/hip_runtime.h>
#include <hip/hip_bf16.h>
#include <stdint.h>

#define S_LEN   2048
#define DIN     2048
#define NHEADS  32
#define HDIM    64
#define NKV     8

typedef __bf16 bf16x8 __attribute__((ext_vector_type(8)));
typedef float  f32x4  __attribute__((ext_vector_type(4)));

#define AS1(p) ((__attribute__((address_space(1))) void*)(void*)(p))
#define AS3(p) ((__attribute__((address_space(3))) void*)(p))
#define MFMA_BF16 __builtin_amdgcn_mfma_f32_16x16x32_bf16

#if __has_builtin(__builtin_amdgcn_exp2f)
#define EXP2F(x) __builtin_amdgcn_exp2f(x)
#else
#define EXP2F(x) exp2f(x)
#endif

static __device__ __forceinline__ unsigned short f2bf(float f) {
  unsigned int x = __float_as_uint(f);
  return (unsigned short)((x + 0x7fffu + ((x >> 16) & 1u)) >> 16);
}

// ---------------- cast x (fp32 -> bf16), vectorized ----------------
__global__ __launch_bounds__(256) void cast_x_kernel(const float* __restrict__ x,
                                                     unsigned short* __restrict__ xb, int n4) {
  int i = blockIdx.x * 256 + threadIdx.x;
  if (i >= n4) return;
  float4 f = ((const float4*)x)[i];
  ushort4 o = make_ushort4(f2bf(f.x), f2bf(f.y), f2bf(f.z), f2bf(f.w));
  ((ushort4*)xb)[i] = o;
}

// ---------------- transpose + cast: src fp32 [K][N] -> dst bf16 [N][K] ----------------
__global__ __launch_bounds__(256) void transpose_cast(const float* __restrict__ src,
                                                      unsigned short* __restrict__ dst,
                                                      int K, int N) {
  __shared__ float t[32][33];
  int n0 = blockIdx.x * 32, k0 = blockIdx.y * 32;
  int x = threadIdx.x, y = threadIdx.y;
  #pragma unroll
  for (int j = 0; j < 32; j += 8)
    t[y + j][x] = src[(size_t)(k0 + y + j) * N + n0 + x];
  __syncthreads();
  #pragma unroll
  for (int j = 0; j < 32; j += 8)
    dst[(size_t)(n0 + y + j) * K + k0 + x] = f2bf(t[x][y + j]);
}

// ---------------- bf16 NT GEMM: C[M][N] fp32 = A[M][K] * Bt[N][K]^T ----------------
// m97 structure + XOR-swizzled LDS (swizzle realized via per-lane global address
// permutation in global_load_lds; consumer reads land 2-way/bank = free).
__global__ __launch_bounds__(256) void gemm_nt(const unsigned short* __restrict__ A,
                                               const unsigned short* __restrict__ Bt,
                                               float* __restrict__ C,
                                               int M, int N, int K) {
  __shared__ alignas(16) unsigned short As[128 * 32];
  __shared__ alignas(16) unsigned short Bs[128 * 32];
  const int tid = threadIdx.x;
  const int wave = tid >> 6, lane = tid & 63;
  const int g = lane >> 4, c = lane & 15;
  const int m0 = blockIdx.y * 128, n0 = blockIdx.x * 128;
  const int wm = (wave & 1) * 64, wn = (wave >> 1) * 64;

  f32x4 acc[4][4] = {};

  const int ch0 = wave * 2;
  const int p0 = ch0 * 64 + lane, p1 = p0 + 64;
  const int r0 = p0 >> 2, gc0 = ((p0 & 3) ^ ((r0 >> 1) & 3)) * 8;
  const int r1 = p1 >> 2, gc1 = ((p1 & 3) ^ ((r1 >> 1) & 3)) * 8;
  const unsigned short* a0 = A + (size_t)(m0 + r0) * K + gc0;
  const unsigned short* a1 = A + (size_t)(m0 + r1) * K + gc1;
  const unsigned short* b0 = Bt + (size_t)(n0 + r0) * K + gc0;
  const unsigned short* b1 = Bt + (size_t)(n0 + r1) * K + gc1;
  const int fswz = (c >> 1) & 3;   // f(row) for consumer rows (wm,i*16 are mult of 16)

  for (int k0 = 0; k0 < K; k0 += 32) {
    __syncthreads();
    __builtin_amdgcn_global_load_lds(AS1(a0 + k0), AS3(As + ch0 * 512), 16, 0, 0);
    __builtin_amdgcn_global_load_lds(AS1(a1 + k0), AS3(As + ch0 * 512 + 512), 16, 0, 0);
    __builtin_amdgcn_global_load_lds(AS1(b0 + k0), AS3(Bs + ch0 * 512), 16, 0, 0);
    __builtin_amdgcn_global_load_lds(AS1(b1 + k0), AS3(Bs + ch0 * 512 + 512), 16, 0, 0);
    __builtin_amdgcn_s_waitcnt(0);
    __syncthreads();

    bf16x8 af[4], bfr[4];
    #pragma unroll
    for (int i = 0; i < 4; i++)
      af[i] = *(const bf16x8*)(As + (wm + i * 16 + c) * 32 + (g ^ fswz) * 8);
    #pragma unroll
    for (int j = 0; j < 4; j++)
      bfr[j] = *(const bf16x8*)(Bs + (wn + j * 16 + c) * 32 + (g ^ fswz) * 8);
    #pragma unroll
    for (int i = 0; i < 4; i++)
      #pragma unroll
      for (int j = 0; j < 4; j++)
        acc[i][j] = MFMA_BF16(af[i], bfr[j], acc[i][j], 0, 0, 0);
  }

  #pragma unroll
  for (int i = 0; i < 4; i++)
    #pragma unroll
    for (int j = 0; j < 4; j++)
      #pragma unroll
      for (int r = 0; r < 4; r++)
        C[(size_t)(m0 + wm + i * 16 + g * 4 + r) * N + n0 + wn + j * 16 + c] = acc[i][j][r];
}

// ---------------- RMSNorm + RoPE for Q and K heads ----------------
// SC = log2(e)/sqrt(64) folded into Q here (attention uses exp2 with fixed max 0).
__global__ __launch_bounds__(256) void norm_rope(const float* __restrict__ QKV,
                                                 const float* __restrict__ cosb,
                                                 const float* __restrict__ sinb,
                                                 const float* __restrict__ q_scale,
                                                 const float* __restrict__ k_scale,
                                                 unsigned short* __restrict__ Qn,
                                                 unsigned short* __restrict__ Kn) {
  const int tid = threadIdx.x, w = tid >> 6, d = tid & 63;
  int task = blockIdx.x * 4 + w;
  const int hid = task % 40;
  const int row = task / 40;            // b*2048 + s
  const int b = row >> 11, s = row & 2047;
  float val, sc;
  if (hid < 32) {
    val = QKV[(size_t)row * 3072 + hid * 64 + d];
    sc = q_scale[d];
  } else {
    val = QKV[(size_t)row * 3072 + 2048 + (hid - 32) * 64 + d];
    sc = k_scale[d];
  }
  float v2 = val * val;
  #pragma unroll
  for (int off = 32; off; off >>= 1) v2 += __shfl_xor(v2, off);
  float t = val * (1.0f / sqrtf(v2 * (1.0f / 64.0f) + 1e-6f)) * sc;
  float partner = __shfl_xor(t, 32);
  float rot = (d < 32) ? -partner : partner;
  float o = t * cosb[s * 64 + d] + rot * sinb[s * 64 + d];
  if (hid < 32) o *= 0.18033688011112042f;   // fold softmax scale into Q
  unsigned short ob = f2bf(o);
  if (hid < 32) Qn[((size_t)(b * 32 + hid) * 2048 + s) * 64 + d] = ob;
  else          Kn[((size_t)(b * 8 + (hid - 32)) * 2048 + s) * 64 + d] = ob;
}

// ---------------- V transpose+cast: QKV fp32 V-cols -> Vt bf16 [b][kv][D][S] ----------------
__global__ __launch_bounds__(256) void v_transpose(const float* __restrict__ QKV,
                                                   unsigned short* __restrict__ Vt) {
  __shared__ float t[64][65];
  int bid = blockIdx.x;
  const int st = bid & 31, kv = (bid >> 5) & 7, b = bid >> 8;
  const int tid = threadIdx.x, lane = tid & 63, quad = tid >> 6;
  #pragma unroll
  for (int p = 0; p < 16; p++) {
    int sl = p * 4 + quad;
    t[sl][lane] = QKV[(size_t)(b * 2048 + st * 64 + sl) * 3072 + 2560 + kv * 64 + lane];
  }
  __syncthreads();
  size_t base = (size_t)(b * 8 + kv) * 64 * 2048;
  #pragma unroll
  for (int p = 0; p < 16; p++) {
    int dd = p * 4 + quad;
    Vt[base + (size_t)dd * 2048 + st * 64 + lane] = f2bf(t[lane][dd]);
  }
}

// ---------------- causal flash attention v3 ----------------
// v2 structure (barrier-free kv loop, fixed-max softmax, S^T orientation) plus:
//  - register double-buffer prefetch of next tile's K (hides ~200-900cyc VMEM lat)
//  - lgkmcnt(0)-only wait (0xC07F) for the P LDS round-trip: vmcnt never drained
//    mid-loop so prefetched K / in-flight V stay outstanding
//  - v_exp_f32 via builtin (1 instr vs ~6 ocml) and P bf16 pack via +0x8000 +
//    v_perm_b32 (round-half-up; 6 instr per 4 values vs 12)
__global__ __launch_bounds__(256) void attn_kernel(const unsigned short* __restrict__ Qn,
                                                   const unsigned short* __restrict__ Kn,
                                                   const unsigned short* __restrict__ Vt,
                                                   unsigned short* __restrict__ Outv) {
  __shared__ alignas(16) char smem[4 * 8704 + 512];
  float* Ls_ = (float*)(smem + 4 * 8704);          // [4][32]

  const int tid = threadIdx.x, w = tid >> 6, lane = tid & 63;
  const int g = lane >> 4, c = lane & 15;
  const int bid = blockIdx.x;
  const int qt = 63 - (bid >> 6);                  // longest blocks first
  const int h = (bid >> 1) & 31, b = bid & 1;
  const int kvh = h >> 2;
  const int Q0 = qt * 32;
  const unsigned short* Qp = Qn + ((size_t)(b * NHEADS + h) * S_LEN + Q0) * HDIM;
  const unsigned short* Kp = Kn + (size_t)(b * NKV + kvh) * S_LEN * HDIM;
  const unsigned short* Vp = Vt + (size_t)(b * NKV + kvh) * HDIM * S_LEN;  // [d][s]
  const int ntiles = (qt >> 1) + 1;

  // Q as B-operand: B[k=d][n=q], n = c, k = g*8+j (+t*32)
  bf16x8 bq[2][2];
  #pragma unroll
  for (int iq = 0; iq < 2; iq++)
    #pragma unroll
    for (int t = 0; t < 2; t++)
      bq[iq][t] = *(const bf16x8*)(Qp + (size_t)(iq * 16 + c) * HDIM + t * 32 + g * 8);

  f32x4 OT[4][2] = {};          // O^T tiles: [dt][iq], row=d, col=q
  f32x4 lv[2] = {};             // per-lane l partials (vector)
  char* PwB = smem + w * 8704;  // this wave's P buffer (32 rows x 128 B, swizzled)

  int ti = w;
  bf16x8 ak[4][2];              // current K tile (A-operand: A[m=kv][k=d])
  if (ti < ntiles) {
    const int kv0 = ti * 64;
    #pragma unroll
    for (int jt = 0; jt < 4; jt++)
      #pragma unroll
      for (int t = 0; t < 2; t++)
        ak[jt][t] = *(const bf16x8*)(Kp + (size_t)(kv0 + jt * 16 + c) * HDIM + t * 32 + g * 8);
  }

  while (ti < ntiles) {
    const int kv0 = ti * 64;

    // V tile (A-operand: A[m=d][k=kv]) — issued early, consumed after softmax
    bf16x8 av[4][2];
    #pragma unroll
    for (int dt = 0; dt < 4; dt++)
      #pragma unroll
      for (int t = 0; t < 2; t++)
        av[dt][t] = *(const bf16x8*)(Vp + (size_t)(dt * 16 + c) * S_LEN + kv0 + t * 32 + g * 8);

    // S^T = K · Q^T : rows kv, cols q
    f32x4 Sx[4][2] = {};
    #pragma unroll
    for (int t = 0; t < 2; t++)
      #pragma unroll
      for (int jt = 0; jt < 4; jt++)
        #pragma unroll
        for (int iq = 0; iq < 2; iq++)
          Sx[jt][iq] = MFMA_BF16(ak[jt][t], bq[iq][t], Sx[jt][iq], 0, 0, 0);

    // prefetch next K tile while softmax/PV runs
    const int tin = ti + 4;
    bf16x8 akn[4][2];
    if (tin < ntiles) {
      const int kvn = tin * 64;
      #pragma unroll
      for (int jt = 0; jt < 4; jt++)
        #pragma unroll
        for (int t = 0; t < 2; t++)
          akn[jt][t] = *(const bf16x8*)(Kp + (size_t)(kvn + jt * 16 + c) * HDIM + t * 32 + g * 8);
    }

    if (ti == ntiles - 1) {     // only the final tile crosses the diagonal
      #pragma unroll
      for (int jt = 0; jt < 4; jt++)
        #pragma unroll
        for (int iq = 0; iq < 2; iq++)
          #pragma unroll
          for (int r = 0; r < 4; r++) {
            int kv = kv0 + jt * 16 + g * 4 + r;
            int q  = Q0 + iq * 16 + c;
            if (kv > q) Sx[jt][iq][r] = -1e30f;
          }
    }

    // fixed-max softmax: p = exp2(s); accumulate l per-lane; pack P -> LDS (swizzled)
    #pragma unroll
    for (int jt = 0; jt < 4; jt++)
      #pragma unroll
      for (int iq = 0; iq < 2; iq++) {
        f32x4 p;
        #pragma unroll
        for (int r = 0; r < 4; r++) p[r] = EXP2F(Sx[jt][iq][r]);
        lv[iq] += p;
        uint32_t u0 = __float_as_uint(p[0]) + 0x8000u;
        uint32_t u1 = __float_as_uint(p[1]) + 0x8000u;
        uint32_t u2 = __float_as_uint(p[2]) + 0x8000u;
        uint32_t u3 = __float_as_uint(p[3]) + 0x8000u;
        uint32_t lo = __builtin_amdgcn_perm(u1, u0, 0x07060302u);
        uint32_t hi = __builtin_amdgcn_perm(u3, u2, 0x07060302u);
        int row = iq * 16 + c;                 // local q
        int bytecol = jt * 32 + g * 8;         // kv-contiguous bytes
        uint32_t off = row * 128 + (((bytecol >> 4) ^ (row & 7)) << 4) + (bytecol & 15);
        *(uint2*)(PwB + off) = make_uint2(lo, hi);
      }
    __builtin_amdgcn_s_waitcnt(0xC07F);        // lgkmcnt(0) only — keep VMEM in flight

    // P as B-operand: B[k=kv][n=q]; read back swizzled b128 (wave-private, no barrier)
    bf16x8 bp[2][2];
    #pragma unroll
    for (int iq = 0; iq < 2; iq++)
      #pragma unroll
      for (int t = 0; t < 2; t++) {
        int row = iq * 16 + c;
        int bytecol = t * 64 + g * 16;
        uint32_t off = row * 128 + (((bytecol >> 4) ^ (row & 7)) << 4);
        bp[iq][t] = *(const bf16x8*)(PwB + off);
      }
    #pragma unroll
    for (int t = 0; t < 2; t++)
      #pragma unroll
      for (int dt = 0; dt < 4; dt++)
        #pragma unroll
        for (int iq = 0; iq < 2; iq++)
          OT[dt][iq] = MFMA_BF16(av[dt][t], bp[iq][t], OT[dt][iq], 0, 0, 0);

    #pragma unroll
    for (int jt = 0; jt < 4; jt++)
      #pragma unroll
      for (int t = 0; t < 2; t++)
        ak[jt][t] = akn[jt][t];
    ti = tin;
  }

  // reduce l across the 4 lane-groups (kv was split across g)
  float lsum[2];
  #pragma unroll
  for (int iq = 0; iq < 2; iq++) {
    lsum[iq] = lv[iq][0] + lv[iq][1] + lv[iq][2] + lv[iq][3];
    lsum[iq] += __shfl_xor(lsum[iq], 16);
    lsum[iq] += __shfl_xor(lsum[iq], 32);
  }
  if (g == 0) { Ls_[w * 32 + c] = lsum[0]; Ls_[w * 32 + 16 + c] = lsum[1]; }

  // per-wave partial O^T -> LDS (fp32, stride 68 floats to dodge banks)
  float* Ow = (float*)(smem + w * 8704);
  #pragma unroll
  for (int dt = 0; dt < 4; dt++)
    #pragma unroll
    for (int iq = 0; iq < 2; iq++) {
      int q = iq * 16 + c;
      *(float2*)&Ow[q * 68 + dt * 16 + g * 4]     = make_float2(OT[dt][iq][0], OT[dt][iq][1]);
      *(float2*)&Ow[q * 68 + dt * 16 + g * 4 + 2] = make_float2(OT[dt][iq][2], OT[dt][iq][3]);
    }
  __syncthreads();

  // combine 4 waves, divide by l, write bf16
  const int q = tid >> 3, d0 = (tid & 7) * 8;
  float l = Ls_[q] + Ls_[32 + q] + Ls_[64 + q] + Ls_[96 + q];
  float inv = 1.0f / l;
  float acc[8] = {};
  #pragma unroll
  for (int ww = 0; ww < 4; ww++) {
    const float* Oww = (const float*)(smem + ww * 8704);
    f32x4 u0 = *(const f32x4*)&Oww[q * 68 + d0];
    f32x4 u1 = *(const f32x4*)&Oww[q * 68 + d0 + 4];
    #pragma unroll
    for (int k = 0; k < 4; k++) { acc[k] += u0[k]; acc[4 + k] += u1[k]; }
  }
  unsigned short ob[8];
  #pragma unroll
  for (int k = 0; k < 8; k++) ob[k] = f2bf(acc[k] * inv);
  uint4 pk = make_uint4((uint32_t)ob[0] | ((uint32_t)ob[1] << 16),
                        (uint32_t)ob[2] | ((uint32_t)ob[3] << 16),
                        (uint32_t)ob[4] | ((uint32_t)ob[5] << 16),
                        (uint32_t)ob[6] | ((uint32_t)ob[7] << 16));
  *(uint4*)(Outv + (size_t)(b * S_LEN + Q0 + q) * (NHEADS * HDIM) + h * HDIM + d0) = pk;
}

extern "C" void kernel_launch(void* const* d_in, const int* in_sizes, int n_in,
                              void* d_out, int out_size, void* d_ws, size_t ws_size,
                              hipStream_t stream) {
  const float* x       = (const float*)d_in[0];
  // d_in[1] = mask (causal, implemented analytically)
  const float* cosb    = (const float*)d_in[2];
  const float* sinb    = (const float*)d_in[3];
  const float* Wq      = (const float*)d_in[4];
  const float* Wk      = (const float*)d_in[5];
  const float* Wv      = (const float*)d_in[6];
  const float* Wo      = (const float*)d_in[7];
  const float* q_scale = (const float*)d_in[8];
  const float* k_scale = (const float*)d_in[9];

  char* ws = (char*)d_ws;
  unsigned short* xb   = (unsigned short*)(ws);                       // 16 MiB: x bf16 [4096][2048]
  unsigned short* wcat = (unsigned short*)(ws + (16ull << 20));       // 12 MiB: Wt [3072][2048]
  unsigned short* wo_t = (unsigned short*)(ws + (28ull << 20));       //  8 MiB: Wo_t [2048][2048]
  float*          qkv  = (float*)        (ws + (36ull << 20));        // 48 MiB: QKV fp32 [4096][3072]
  unsigned short* qn   = (unsigned short*)(ws + (84ull << 20));       // 16 MiB: Q bf16 [b][h][s][d]
  unsigned short* kn   = (unsigned short*)(ws + (100ull << 20));      //  4 MiB: K bf16 [b][kv][s][d]
  unsigned short* vt   = (unsigned short*)(ws + (104ull << 20));      //  4 MiB: V^T bf16 [b][kv][d][s]
  unsigned short* vec  = (unsigned short*)(ws + (36ull << 20));       // alias qkv (dead after v_transpose)

  cast_x_kernel<<<8192, 256, 0, stream>>>(x, xb, 2097152);
  dim3 tb(32, 8);
  transpose_cast<<<dim3(64, 64), tb, 0, stream>>>(Wq, wcat,               2048, 2048);
  transpose_cast<<<dim3(16, 64), tb, 0, stream>>>(Wk, wcat + 2048 * 2048, 2048, 512);
  transpose_cast<<<dim3(16, 64), tb, 0, stream>>>(Wv, wcat + 2560 * 2048, 2048, 512);
  transpose_cast<<<dim3(64, 64), tb, 0, stream>>>(Wo, wo_t,               2048, 2048);

  gemm_nt<<<dim3(24, 32), 256, 0, stream>>>(xb, wcat, qkv, 4096, 3072, 2048);
  norm_rope<<<40960, 256, 0, stream>>>(qkv, cosb, sinb, q_scale, k_scale, qn, kn);
  v_transpose<<<512, 256, 0, stream>>>(qkv, vt);
  attn_kernel<<<4096, 256, 0, stream>>>(qn, kn, vt, vec);
  gemm_nt<<<dim3(16, 32), 256, 0, stream>>>(vec, wo_t, (float*)d_out, 4096, 2048, 2048);
}